// Round 4
// baseline (712.894 us; speedup 1.0000x reference)
//
#include <hip/hip_runtime.h>

// SSIM 3D, round 4: barrier-free main loop.
// Separable rank-1 window (u ⊗ v ⊗ t), fused W->H->D as in R3, but the
// H-exchange is WAVE-PRIVATE: each wave owns an 8-row x 32-col tile and a
// private 5 KB LDS region. Cross-lane RAW inside one wave needs only
// s_waitcnt lgkmcnt(0) (DS ops are in-order per wave) + wave_barrier to pin
// compiler ordering — zero __syncthreads in the 12-phase loop.
// Tile per wave: 4 out-rows x 32 cols; block = 4 waves = 4 rows x 128 cols.
// DSUB=8 -> grid 2048 (8 blocks/CU potential; ~6 with VGPR/LDS limits).

#define NDIM 128
#define TH 4
#define WR 8                    // W-conv rows per wave (TH + 4 halo)
#define DSUB 8
#define NPH (DSUB + 4)          // 12 phases
#define NHT (NDIM / TH)         // 32
#define NDT (NDIM / DSUB)       // 16
#define NB 4
#define NBLK (NHT * NDT * NB)   // 2048

// s_waitcnt simm16 for "lgkmcnt(0) only": vmcnt=0x3f, expcnt=7, lgkmcnt=0
#define LGKM0 0xC07F

__global__ void factorize_window(const float* __restrict__ w, float* __restrict__ ws) {
    if (threadIdx.x == 0) {
        float w000 = w[0];
        #pragma unroll
        for (int i = 0; i < 5; ++i) ws[i]      = w[i * 25];
        #pragma unroll
        for (int j = 0; j < 5; ++j) ws[5 + j]  = w[j * 5] / w000;
        #pragma unroll
        for (int k = 0; k < 5; ++k) ws[10 + k] = w[k] / w000;
    }
}

__launch_bounds__(256, 6)
__global__ void ssim_main(const float* __restrict__ img1,
                          const float* __restrict__ img2,
                          const float* __restrict__ wfac,
                          float* __restrict__ partials) {
    const int bid = blockIdx.x;
    const int th = bid % NHT;
    const int td = (bid / NHT) % NDT;
    const int b  = bid / (NHT * NDT);

    const int h0 = th * TH, d0 = td * DSUB;
    const float* __restrict__ x1 = img1 + (size_t)(b * 2 + 1) * NDIM * NDIM * NDIM;
    const float* __restrict__ x2 = img2 + (size_t)b * NDIM * NDIM * NDIM;

    float uW[5], vW[5], tW[5];
    #pragma unroll
    for (int i = 0; i < 5; ++i) { uW[i] = wfac[i]; vW[i] = wfac[5 + i]; tW[i] = wfac[10 + i]; }

    __shared__ float sWc[4][5][WR][32];   // [wave][field][row][col] = 20 KB
    __shared__ float sRed[4];

    const int tid  = threadIdx.x;
    const int wid  = tid >> 6;
    const int lane = tid & 63;
    // W-conv role: 8 rows x 8 col-groups of 4 (per wave)
    const int wrow = lane >> 3;
    const int wcg  = lane & 7;
    const int c0   = wid * 32 + wcg * 4;      // global col of first owned col
    const int ghw  = h0 + wrow - 2;
    const bool haveL = (c0 >= 4);
    const bool haveR = (c0 <= 120);
    // H/D role: 4 out-rows x 16 col-pairs (per wave)
    const int orow = lane >> 4;
    const int lc   = (lane & 15) * 2;         // local col within wave tile

    float2 ring[5][5];                        // [slot][field], static indices
    float2 accS = make_float2(0.f, 0.f);

#define PHASE(I, P) do {                                                       \
    const int i_ = (I);                                                        \
    const int d_ = d0 - 2 + i_;                                                \
    float4 A0 = make_float4(0,0,0,0), A1 = A0, A2 = A0;                        \
    float4 B0 = A0, B1 = A0, B2 = A0;                                          \
    if (((unsigned)d_ < NDIM) && ((unsigned)ghw < NDIM)) {                     \
        const float* __restrict__ r1_ = x1 + ((size_t)d_ * NDIM + ghw) * NDIM; \
        const float* __restrict__ r2_ = x2 + ((size_t)d_ * NDIM + ghw) * NDIM; \
        if (haveL) { A0 = *(const float4*)(r1_ + c0 - 4);                      \
                     B0 = *(const float4*)(r2_ + c0 - 4); }                    \
        A1 = *(const float4*)(r1_ + c0);                                       \
        B1 = *(const float4*)(r2_ + c0);                                       \
        if (haveR) { A2 = *(const float4*)(r1_ + c0 + 4);                      \
                     B2 = *(const float4*)(r2_ + c0 + 4); }                    \
    }                                                                          \
    const float ra[12] = {A0.x,A0.y,A0.z,A0.w, A1.x,A1.y,A1.z,A1.w,            \
                          A2.x,A2.y,A2.z,A2.w};                                \
    const float rb[12] = {B0.x,B0.y,B0.z,B0.w, B1.x,B1.y,B1.z,B1.w,            \
                          B2.x,B2.y,B2.z,B2.w};                                \
    float m1v[4], m2v[4], q11v[4], q22v[4], q12v[4];                           \
    _Pragma("unroll")                                                          \
    for (int k_ = 0; k_ < 4; ++k_) {                                           \
        float m1_=0.f, m2_=0.f, q11_=0.f, q22_=0.f, q12_=0.f;                  \
        _Pragma("unroll")                                                      \
        for (int c_ = 0; c_ < 5; ++c_) {                                       \
            const float a_ = ra[k_ + c_ + 2], b_ = rb[k_ + c_ + 2];            \
            const float t_ = tW[c_];                                           \
            const float ta_ = t_ * a_, tb_ = t_ * b_;                          \
            m1_ += ta_; m2_ += tb_;                                            \
            q11_ += ta_ * a_; q22_ += tb_ * b_; q12_ += ta_ * b_;              \
        }                                                                      \
        m1v[k_]=m1_; m2v[k_]=m2_; q11v[k_]=q11_; q22v[k_]=q22_; q12v[k_]=q12_; \
    }                                                                          \
    __builtin_amdgcn_wave_barrier();                                           \
    *(float4*)&sWc[wid][0][wrow][wcg*4] = make_float4(m1v[0],m1v[1],m1v[2],m1v[3]); \
    *(float4*)&sWc[wid][1][wrow][wcg*4] = make_float4(m2v[0],m2v[1],m2v[2],m2v[3]); \
    *(float4*)&sWc[wid][2][wrow][wcg*4] = make_float4(q11v[0],q11v[1],q11v[2],q11v[3]); \
    *(float4*)&sWc[wid][3][wrow][wcg*4] = make_float4(q22v[0],q22v[1],q22v[2],q22v[3]); \
    *(float4*)&sWc[wid][4][wrow][wcg*4] = make_float4(q12v[0],q12v[1],q12v[2],q12v[3]); \
    __builtin_amdgcn_wave_barrier();                                           \
    __builtin_amdgcn_s_waitcnt(LGKM0);  /* same-wave DS RAW: writes visible */ \
    __builtin_amdgcn_wave_barrier();                                           \
    _Pragma("unroll")                                                          \
    for (int f_ = 0; f_ < 5; ++f_) {                                           \
        float2 F_ = make_float2(0.f, 0.f);                                     \
        _Pragma("unroll")                                                      \
        for (int r_ = 0; r_ < 5; ++r_) {                                       \
            const float2 wv_ = *(const float2*)&sWc[wid][f_][orow + r_][lc];   \
            F_.x += vW[r_] * wv_.x;                                            \
            F_.y += vW[r_] * wv_.y;                                            \
        }                                                                      \
        ring[(P)][f_] = F_;                                                    \
    }                                                                          \
    __builtin_amdgcn_wave_barrier();    /* pin next phase's stores below */    \
    if (i_ >= 4) {                                                             \
        float2 F0 = make_float2(0,0), F1 = F0, F2 = F0, F3 = F0, F4 = F0;      \
        _Pragma("unroll")                                                      \
        for (int j_ = 0; j_ < 5; ++j_) {                                       \
            const int s_ = ((P) + 1 + j_) % 5;                                 \
            const float uw_ = uW[j_];                                          \
            F0.x += uw_*ring[s_][0].x; F0.y += uw_*ring[s_][0].y;              \
            F1.x += uw_*ring[s_][1].x; F1.y += uw_*ring[s_][1].y;              \
            F2.x += uw_*ring[s_][2].x; F2.y += uw_*ring[s_][2].y;              \
            F3.x += uw_*ring[s_][3].x; F3.y += uw_*ring[s_][3].y;              \
            F4.x += uw_*ring[s_][4].x; F4.y += uw_*ring[s_][4].y;              \
        }                                                                      \
        {                                                                      \
            const float mu1 = F0.x, mu2 = F1.x;                                \
            const float m11 = mu1*mu1, m22 = mu2*mu2, m12 = mu1*mu2;           \
            const float num = (2.f*m12 + 1e-4f) * (2.f*(F4.x - m12) + 9e-4f);  \
            const float den = (m11 + m22 + 1e-4f) *                            \
                              ((F2.x - m11) + (F3.x - m22) + 9e-4f);           \
            accS.x += __fdividef(num, den);                                    \
        }                                                                      \
        {                                                                      \
            const float mu1 = F0.y, mu2 = F1.y;                                \
            const float m11 = mu1*mu1, m22 = mu2*mu2, m12 = mu1*mu2;           \
            const float num = (2.f*m12 + 1e-4f) * (2.f*(F4.y - m12) + 9e-4f);  \
            const float den = (m11 + m22 + 1e-4f) *                            \
                              ((F2.y - m11) + (F3.y - m22) + 9e-4f);           \
            accS.y += __fdividef(num, den);                                    \
        }                                                                      \
    }                                                                          \
} while (0)

    // 12 phases: d0-2 .. d0+9; ring phase = i % 5
    PHASE(0, 0);  PHASE(1, 1);  PHASE(2, 2);  PHASE(3, 3);  PHASE(4, 4);
    PHASE(5, 0);  PHASE(6, 1);  PHASE(7, 2);  PHASE(8, 3);  PHASE(9, 4);
    PHASE(10, 0); PHASE(11, 1);
#undef PHASE

    float acc = accS.x + accS.y;
    #pragma unroll
    for (int off = 32; off > 0; off >>= 1)
        acc += __shfl_down(acc, off, 64);
    __syncthreads();
    if ((tid & 63) == 0) sRed[tid >> 6] = acc;
    __syncthreads();
    if (tid == 0) partials[bid] = sRed[0] + sRed[1] + sRed[2] + sRed[3];
}

__global__ void finalize_kernel(const float* __restrict__ partials, float* __restrict__ out) {
    const int tid = threadIdx.x;
    double s = 0.0;
    for (int i = tid; i < NBLK; i += 256) s += (double)partials[i];
    #pragma unroll
    for (int off = 32; off > 0; off >>= 1)
        s += __shfl_down(s, off, 64);
    __shared__ double sm[4];
    if ((tid & 63) == 0) sm[tid >> 6] = s;
    __syncthreads();
    if (tid == 0)
        out[0] = 1.0f - (float)((sm[0] + sm[1] + sm[2] + sm[3]) / (double)(4LL * 128 * 128 * 128));
}

extern "C" void kernel_launch(void* const* d_in, const int* in_sizes, int n_in,
                              void* d_out, int out_size, void* d_ws, size_t ws_size,
                              hipStream_t stream) {
    const float* img1 = (const float*)d_in[0];   // (4,2,128,128,128) fp32
    const float* img2 = (const float*)d_in[1];   // (4,1,128,128,128) fp32
    const float* win  = (const float*)d_in[2];   // (1,1,5,5,5) fp32
    float* out = (float*)d_out;
    float* ws  = (float*)d_ws;
    float* wfac     = ws;         // 16 floats
    float* partials = ws + 16;    // NBLK floats, fully rewritten every launch

    hipLaunchKernelGGL(factorize_window, dim3(1), dim3(64), 0, stream, win, wfac);
    hipLaunchKernelGGL(ssim_main, dim3(NBLK), dim3(256), 0, stream, img1, img2, wfac, partials);
    hipLaunchKernelGGL(finalize_kernel, dim3(1), dim3(256), 0, stream, partials, out);
}